// Round 3
// baseline (515.033 us; speedup 1.0000x reference)
//
#include <hip/hip_runtime.h>
#include <hip/hip_bf16.h>
#include <stdint.h>

typedef __attribute__((ext_vector_type(8))) short short8;
typedef __attribute__((ext_vector_type(4))) float floatx4;

#define NB 4
#define NN 8192
#define NC 768
#define NH 12
#define ND 64
#define LDQKV 2304
#define NSPLIT 16   // n-splits for kv/attn kernels

// ---------- helpers ----------
__device__ __forceinline__ float bf2f(ushort u) {
    union { float f; uint32_t i; } x; x.i = ((uint32_t)u) << 16; return x.f;
}
__device__ __forceinline__ ushort f2bf(float f) {
    union { float f; uint32_t i; } x; x.f = f;
    uint32_t r = x.i + 0x7fff + ((x.i >> 16) & 1);
    return (ushort)(r >> 16);
}
typedef const __attribute__((address_space(1))) uint32_t* gas1_t;
typedef __attribute__((address_space(3))) uint32_t* las3_t;
__device__ __forceinline__ void gl_lds16(const void* g, const void* l) {
    __builtin_amdgcn_global_load_lds((gas1_t)(uintptr_t)g,
                                     (las3_t)(uint32_t)(uintptr_t)l, 16, 0, 0);
}

// ---------- fp32 -> bf16 bulk convert of X, Wqkv, Wproj in one launch ----------
__global__ __launch_bounds__(256) void cvt_all(const float* __restrict__ X,
                                               const float* __restrict__ Wq,
                                               const float* __restrict__ Wp,
                                               ushort* __restrict__ xbf,
                                               ushort* __restrict__ wqbf,
                                               ushort* __restrict__ wpbf) {
    const int nx = 32768 * 768, nwq = 2304 * 768, nwp = 768 * 768;
    int i = (blockIdx.x * 256 + threadIdx.x) * 8;
    const float* src; ushort* dst;
    if (i < nx)            { src = X + i;              dst = xbf + i; }
    else if (i < nx + nwq) { i -= nx;  src = Wq + i;   dst = wqbf + i; }
    else                   { i -= nx + nwq; if (i >= nwp) return; src = Wp + i; dst = wpbf + i; }
    const float4 a = *(const float4*)src;
    const float4 b = *(const float4*)(src + 4);
    short8 v;
    v[0] = (short)f2bf(a.x); v[1] = (short)f2bf(a.y);
    v[2] = (short)f2bf(a.z); v[3] = (short)f2bf(a.w);
    v[4] = (short)f2bf(b.x); v[5] = (short)f2bf(b.y);
    v[6] = (short)f2bf(b.z); v[7] = (short)f2bf(b.w);
    *(short8*)dst = v;
}

// ---------- GEMM: C[M, n-slice] = act(A[M,K] @ Bw[N,K]^T (+ bias)) ----------
// 128x128 block tile, BK=64 as two 32-col panels (keeps 64B-row LDS layout and
// gl_lds16 lane->base+16*lane contiguity). 4 waves 2x2, 4x4 16x16x32 MFMA each.
template<int LDC, bool ELU, bool BIAS, typename OutT>
__global__ __launch_bounds__(256) void gemm_bt(const ushort* __restrict__ A,
                                               const ushort* __restrict__ Bw,
                                               const float* __restrict__ bias,
                                               OutT* __restrict__ Cout, int K) {
    __shared__ ushort As[2][128 * 32];   // [panel][row*32 + k]
    __shared__ ushort Bs[2][128 * 32];
    const int t = threadIdx.x;
    const int w = t >> 6, lane = t & 63, l16 = lane & 15, quad = lane >> 4;
    const int wm = w & 1, wn = w >> 1;
    const int m0 = blockIdx.y * 128, n0 = blockIdx.x * 128;

    floatx4 acc[4][4] = {};

    const int rowA = t >> 2, chA = t & 3;   // 64 rows x 4 chunks of 16B => lane lands at base+16*lane
    const ushort* gA = A  + (size_t)(m0 + rowA) * K + chA * 8;
    const ushort* gB = Bw + (size_t)(n0 + rowA) * K + chA * 8;

    for (int k0 = 0; k0 < K; k0 += 64) {
        #pragma unroll
        for (int p = 0; p < 2; p++) {
            gl_lds16(gA + k0 + p * 32,                &As[p][w * 512]);
            gl_lds16(gA + k0 + p * 32 + 64 * (size_t)K, &As[p][2048 + w * 512]);
            gl_lds16(gB + k0 + p * 32,                &Bs[p][w * 512]);
            gl_lds16(gB + k0 + p * 32 + 64 * (size_t)K, &Bs[p][2048 + w * 512]);
        }
        __syncthreads();
        #pragma unroll
        for (int p = 0; p < 2; p++) {
            short8 af[4], bfr[4];
            #pragma unroll
            for (int i = 0; i < 4; i++)
                af[i] = *(const short8*)&As[p][(wm * 64 + i * 16 + l16) * 32 + quad * 8];
            #pragma unroll
            for (int j = 0; j < 4; j++)
                bfr[j] = *(const short8*)&Bs[p][(wn * 64 + j * 16 + l16) * 32 + quad * 8];
            #pragma unroll
            for (int i = 0; i < 4; i++)
                #pragma unroll
                for (int j = 0; j < 4; j++)
                    acc[i][j] = __builtin_amdgcn_mfma_f32_16x16x32_bf16(af[i], bfr[j], acc[i][j], 0, 0, 0);
        }
        __syncthreads();
    }

    #pragma unroll
    for (int i = 0; i < 4; i++) {
        const int row = m0 + wm * 64 + i * 16 + quad * 4;
        #pragma unroll
        for (int j = 0; j < 4; j++) {
            const int col = n0 + wn * 64 + j * 16 + l16;
            float bval = 0.f;
            if (BIAS) bval = bias[col];
            OutT* cp = Cout + (size_t)row * LDC + col;
            #pragma unroll
            for (int r = 0; r < 4; r++) {
                float v = acc[i][j][r];
                if (ELU) { if (col < 2 * NC) v = (v > 0.f) ? v + 1.f : __expf(v); }
                if (BIAS) v += bval;
                if (sizeof(OutT) == 2) *cp = (OutT)f2bf(v);
                else                   *cp = (OutT)v;
                cp += LDC;
            }
        }
    }
}

// ---------- kv/ksum partials: per (slice, bh) block over 512 rows ----------
// kv[d,e] += k[n,d] v[n,e]; ksum via ones-column MFMA frag (B[n][0]=1).
__global__ __launch_bounds__(256) void kv_ksum(const ushort* __restrict__ qkv,
                                               float* __restrict__ kvpart,
                                               float* __restrict__ kspart) {
    __shared__ ushort klds[128 * 64];
    __shared__ ushort vlds[128 * 64];
    __shared__ float  kvred[64 * 64];
    __shared__ float  ksred[4][64];
    const int bh = blockIdx.y, b = bh / NH, h = bh % NH;
    const int t = threadIdx.x, w = t >> 6, lane = t & 63, l16 = lane & 15, quad = lane >> 4;
    const int n0 = blockIdx.x * (NN * NB / NSPLIT / 4);   // 512 rows per block
    const ushort* kbase = qkv + (size_t)(b * NN) * LDQKV + NC     + h * ND;
    const ushort* vbase = qkv + (size_t)(b * NN) * LDQKV + 2 * NC + h * ND;

    floatx4 acc[4][4] = {};
    floatx4 acc5[4] = {};
    short8 ones;
    #pragma unroll
    for (int j = 0; j < 8; j++) ones[j] = (l16 == 0) ? (short)0x3F80 : (short)0;

    const int rowT = t >> 3, ch = t & 7;   // 32 rows x 8 chunks of 16B

    for (int s = 0; s < 4; s++) {
        const int nb = n0 + s * 128;
        #pragma unroll
        for (int i = 0; i < 4; i++) {
            const size_t r = (size_t)(nb + i * 32 + rowT) * LDQKV + ch * 8;
            gl_lds16(kbase + r, klds + i * 2048 + w * 512);
            gl_lds16(vbase + r, vlds + i * 2048 + w * 512);
        }
        __syncthreads();
        short8 af[4], bfr[4];
        #pragma unroll
        for (int dt = 0; dt < 4; dt++) {
            short8 v;
            #pragma unroll
            for (int j = 0; j < 8; j++)
                v[j] = (short)klds[(w * 32 + quad * 8 + j) * 64 + dt * 16 + l16];
            af[dt] = v;
        }
        #pragma unroll
        for (int et = 0; et < 4; et++) {
            short8 v;
            #pragma unroll
            for (int j = 0; j < 8; j++)
                v[j] = (short)vlds[(w * 32 + quad * 8 + j) * 64 + et * 16 + l16];
            bfr[et] = v;
        }
        #pragma unroll
        for (int dt = 0; dt < 4; dt++) {
            #pragma unroll
            for (int et = 0; et < 4; et++)
                acc[dt][et] = __builtin_amdgcn_mfma_f32_16x16x32_bf16(af[dt], bfr[et], acc[dt][et], 0, 0, 0);
            acc5[dt] = __builtin_amdgcn_mfma_f32_16x16x32_bf16(af[dt], ones, acc5[dt], 0, 0, 0);
        }
        __syncthreads();
    }

    if (w == 0) {
        #pragma unroll
        for (int dt = 0; dt < 4; dt++)
            #pragma unroll
            for (int et = 0; et < 4; et++)
                #pragma unroll
                for (int r = 0; r < 4; r++)
                    kvred[(dt * 16 + quad * 4 + r) * 64 + et * 16 + l16] = acc[dt][et][r];
    }
    if (l16 == 0) {
        #pragma unroll
        for (int dt = 0; dt < 4; dt++)
            #pragma unroll
            for (int r = 0; r < 4; r++)
                ksred[w][dt * 16 + quad * 4 + r] = acc5[dt][r];
    }
    __syncthreads();
    if (w != 0) {
        #pragma unroll
        for (int dt = 0; dt < 4; dt++)
            #pragma unroll
            for (int et = 0; et < 4; et++)
                #pragma unroll
                for (int r = 0; r < 4; r++)
                    atomicAdd(&kvred[(dt * 16 + quad * 4 + r) * 64 + et * 16 + l16], acc[dt][et][r]);
    }
    __syncthreads();
    float* kvp = kvpart + ((size_t)blockIdx.x * 48 + bh) * 4096;
    for (int i = t; i < 4096; i += 256) kvp[i] = kvred[i];
    if (t < 64) kspart[((size_t)blockIdx.x * 48 + bh) * 64 + t] =
        ksred[0][t] + ksred[1][t] + ksred[2][t] + ksred[3][t];
}

// ---------- reduce partials: kvfinal[bh][4096], ksfinal[bh][64] ----------
__global__ __launch_bounds__(256) void reduce_kvks(const float* __restrict__ kvpart,
                                                   const float* __restrict__ kspart,
                                                   float* __restrict__ kvfinal,
                                                   float* __restrict__ ksfinal) {
    const int bh = blockIdx.y, t = threadIdx.x;
    if (blockIdx.x < 16) {
        const int i = blockIdx.x * 256 + t;
        float s = 0.f;
        #pragma unroll
        for (int p = 0; p < NSPLIT; p++) s += kvpart[((size_t)p * 48 + bh) * 4096 + i];
        kvfinal[(size_t)bh * 4096 + i] = s;
    } else if (t < 64) {
        float s = 0.f;
        #pragma unroll
        for (int p = 0; p < NSPLIT; p++) s += kspart[((size_t)p * 48 + bh) * 64 + t];
        ksfinal[bh * 64 + t] = s;
    }
}

// ---------- out_pre[b,n,h*64+e] = (q[n,:] @ kv) / (q[n,:]·ksum + 1e-6), bf16 ----------
__global__ __launch_bounds__(256) void attn_apply(const ushort* __restrict__ qkv,
                                                  const float* __restrict__ kvfinal,
                                                  const float* __restrict__ ksfinal,
                                                  ushort* __restrict__ outpre) {
    __shared__ ushort kvb[64 * 80];
    const int bh = blockIdx.y, b = bh / NH, h = bh % NH;
    const int t = threadIdx.x, w = t >> 6, lane = t & 63, l16 = lane & 15, quad = lane >> 4;

    for (int i = t; i < 4096; i += 256) {
        const int d = i >> 6, e = i & 63;
        kvb[d * 80 + e] = f2bf(kvfinal[(size_t)bh * 4096 + i]);
    }
    for (int i = t; i < 1024; i += 256) {
        const int d = i >> 4, c = i & 15;
        kvb[d * 80 + 64 + c] = (c == 0) ? f2bf(ksfinal[bh * 64 + d]) : (ushort)0;
    }
    __syncthreads();

    short8 bfr[5][2];
    #pragma unroll
    for (int et = 0; et < 5; et++)
        #pragma unroll
        for (int ks = 0; ks < 2; ks++) {
            short8 v;
            #pragma unroll
            for (int j = 0; j < 8; j++)
                v[j] = (short)kvb[(ks * 32 + quad * 8 + j) * 80 + et * 16 + l16];
            bfr[et][ks] = v;
        }

    const ushort* qbase = qkv + (size_t)(b * NN) * LDQKV + h * ND;
    ushort* obase = outpre + (size_t)(b * NN) * NC + h * ND;
    const int n0 = blockIdx.x * (NN * NB / NSPLIT / 4);   // 512 rows

    for (int it = 0; it < 8; it++) {
        const int nt = n0 + (it * 4 + w) * 16;
        const ushort* qp = qbase + (size_t)(nt + l16) * LDQKV + quad * 8;
        const short8 a0 = *(const short8*)qp;
        const short8 a1 = *(const short8*)(qp + 32);
        floatx4 acc[5] = {};
        #pragma unroll
        for (int et = 0; et < 5; et++) {
            acc[et] = __builtin_amdgcn_mfma_f32_16x16x32_bf16(a0, bfr[et][0], acc[et], 0, 0, 0);
            acc[et] = __builtin_amdgcn_mfma_f32_16x16x32_bf16(a1, bfr[et][1], acc[et], 0, 0, 0);
        }
        float dv[4];
        #pragma unroll
        for (int r = 0; r < 4; r++) dv[r] = __shfl(acc[4][r], lane & 48);
        #pragma unroll
        for (int et = 0; et < 4; et++)
            #pragma unroll
            for (int r = 0; r < 4; r++) {
                const float o = acc[et][r] / (dv[r] + 1e-6f);
                obase[(size_t)(nt + quad * 4 + r) * NC + et * 16 + l16] = f2bf(o);
            }
    }
}

extern "C" void kernel_launch(void* const* d_in, const int* in_sizes, int n_in,
                              void* d_out, int out_size, void* d_ws, size_t ws_size,
                              hipStream_t stream) {
    (void)in_sizes; (void)n_in; (void)out_size; (void)ws_size;
    const float* X     = (const float*)d_in[0];   // [4,8192,768] fp32
    const float* Wqkv  = (const float*)d_in[1];   // [2304,768]   fp32
    const float* Wproj = (const float*)d_in[2];   // [768,768]    fp32
    const float* bproj = (const float*)d_in[3];   // [768]        fp32
    float* out = (float*)d_out;                   // [4,8192,768] fp32

    char* ws = (char*)d_ws;
    size_t off = 0;
    ushort* qkv     = (ushort*)(ws + off); off += (size_t)32768 * 2304 * 2;  // 151.0 MB
    ushort* outpre  = (ushort*)(ws + off); off += (size_t)32768 * 768 * 2;   //  50.3 MB
    ushort* xbf     = (ushort*)(ws + off); off += (size_t)32768 * 768 * 2;   //  50.3 MB
    ushort* wqkvbf  = (ushort*)(ws + off); off += (size_t)2304 * 768 * 2;    //   3.5 MB
    ushort* wprojbf = (ushort*)(ws + off); off += (size_t)768 * 768 * 2;     //   1.2 MB
    // kv partials/finals alias the xbf region (dead after the qkv GEMM):
    float* kvpart  = (float*)xbf;                               // 16*48*4096*4 = 12.6 MB
    float* kspart  = kvpart + (size_t)NSPLIT * 48 * 4096;       // 196 KB
    float* kvfinal = kspart + (size_t)NSPLIT * 48 * 64;         // 786 KB
    float* ksfinal = kvfinal + (size_t)48 * 4096;               // 12 KB

    const int ncvt = (32768 * 768 + 2304 * 768 + 768 * 768) / 8 / 256;   // 13440 blocks
    cvt_all<<<ncvt, 256, 0, stream>>>(X, Wqkv, Wproj, xbf, wqkvbf, wprojbf);

    gemm_bt<LDQKV, true, false, ushort><<<dim3(18, 256), 256, 0, stream>>>(xbf, wqkvbf, nullptr, qkv, NC);
    kv_ksum<<<dim3(NSPLIT, 48), 256, 0, stream>>>(qkv, kvpart, kspart);
    reduce_kvks<<<dim3(17, 48), 256, 0, stream>>>(kvpart, kspart, kvfinal, ksfinal);
    attn_apply<<<dim3(NSPLIT, 48), 256, 0, stream>>>(qkv, kvfinal, ksfinal, outpre);
    gemm_bt<NC, false, true, float><<<dim3(6, 256), 256, 0, stream>>>(outpre, wprojbf, bproj, out, NC);
}

// Round 4
// 503.543 us; speedup vs baseline: 1.0228x; 1.0228x over previous
//
#include <hip/hip_runtime.h>
#include <hip/hip_bf16.h>
#include <stdint.h>

typedef __attribute__((ext_vector_type(8))) short short8;
typedef __attribute__((ext_vector_type(4))) float floatx4;
typedef __attribute__((ext_vector_type(16))) float floatx16;

#define NB 4
#define NN 8192
#define NC 768
#define NH 12
#define ND 64
#define LDQKV 2304
#define NSPLIT 16

// ---------- helpers ----------
__device__ __forceinline__ float bf2f(ushort u) {
    union { float f; uint32_t i; } x; x.i = ((uint32_t)u) << 16; return x.f;
}
__device__ __forceinline__ ushort f2bf(float f) {
    union { float f; uint32_t i; } x; x.f = f;
    uint32_t r = x.i + 0x7fff + ((x.i >> 16) & 1);
    return (ushort)(r >> 16);
}
typedef const __attribute__((address_space(1))) uint32_t* gas1_t;
typedef __attribute__((address_space(3))) uint32_t* las3_t;
__device__ __forceinline__ void gl_lds16(const void* g, const void* l) {
    __builtin_amdgcn_global_load_lds((gas1_t)(uintptr_t)g,
                                     (las3_t)(uint32_t)(uintptr_t)l, 16, 0, 0);
}

// ---------- fp32 -> bf16 bulk convert of X, Wqkv, Wproj in one launch ----------
__global__ __launch_bounds__(256) void cvt_all(const float* __restrict__ X,
                                               const float* __restrict__ Wq,
                                               const float* __restrict__ Wp,
                                               ushort* __restrict__ xbf,
                                               ushort* __restrict__ wqbf,
                                               ushort* __restrict__ wpbf) {
    const int nx = 32768 * 768, nwq = 2304 * 768, nwp = 768 * 768;
    int i = (blockIdx.x * 256 + threadIdx.x) * 8;
    const float* src; ushort* dst;
    if (i < nx)            { src = X + i;              dst = xbf + i; }
    else if (i < nx + nwq) { i -= nx;  src = Wq + i;   dst = wqbf + i; }
    else                   { i -= nx + nwq; if (i >= nwp) return; src = Wp + i; dst = wpbf + i; }
    const float4 a = *(const float4*)src;
    const float4 b = *(const float4*)(src + 4);
    short8 v;
    v[0] = (short)f2bf(a.x); v[1] = (short)f2bf(a.y);
    v[2] = (short)f2bf(a.z); v[3] = (short)f2bf(a.w);
    v[4] = (short)f2bf(b.x); v[5] = (short)f2bf(b.y);
    v[6] = (short)f2bf(b.z); v[7] = (short)f2bf(b.w);
    *(short8*)dst = v;
}

// ---------- GEMM: C[M, n-slice] = act(A[M,K] @ Bw[N,K]^T (+ bias)) ----------
// 128x128 tile, BK=32, 4 waves 2x2; per wave 2x2 tiles of 32x32x16 MFMA.
// LDS chunk layout XOR-swizzled: chunk (row, kc) lives at pos row*4 + (kc^(row&3)),
// which keeps gl_lds16's lane->base+16*lane write contiguity AND makes the
// b128 frag reads conflict-free (was 4-way on banks {r*16}%32).
template<int LDC, bool ELU, bool BIAS, typename OutT>
__global__ __launch_bounds__(256) void gemm_bt(const ushort* __restrict__ A,
                                               const ushort* __restrict__ Bw,
                                               const float* __restrict__ bias,
                                               OutT* __restrict__ Cout, int K) {
    __shared__ ushort As[128 * 32];
    __shared__ ushort Bs[128 * 32];
    const int t = threadIdx.x;
    const int w = t >> 6, lane = t & 63, l32 = lane & 31, hi = lane >> 5;
    const int wm = w & 1, wn = w >> 1;
    const int m0 = blockIdx.y * 128, n0 = blockIdx.x * 128;

    floatx16 acc[2][2] = {};

    const int rowA = t >> 2, chA = (t & 3) ^ (rowA & 3);   // swizzled k-chunk fetch
    const ushort* gA = A  + (size_t)(m0 + rowA) * K + chA * 8;
    const ushort* gB = Bw + (size_t)(n0 + rowA) * K + chA * 8;

    for (int k0 = 0; k0 < K; k0 += 32) {
        gl_lds16(gA + k0,                  As + w * 512);
        gl_lds16(gA + k0 + 64 * (size_t)K, As + 2048 + w * 512);
        gl_lds16(gB + k0,                  Bs + w * 512);
        gl_lds16(gB + k0 + 64 * (size_t)K, Bs + 2048 + w * 512);
        __syncthreads();
        short8 af[2][2], bfr[2][2];
        #pragma unroll
        for (int mt = 0; mt < 2; mt++)
            #pragma unroll
            for (int kh = 0; kh < 2; kh++) {
                const int row = wm * 64 + mt * 32 + l32;
                const int kc = kh * 2 + hi;
                af[mt][kh] = *(const short8*)&As[(row * 4 + (kc ^ (row & 3))) * 8];
            }
        #pragma unroll
        for (int nt = 0; nt < 2; nt++)
            #pragma unroll
            for (int kh = 0; kh < 2; kh++) {
                const int row = wn * 64 + nt * 32 + l32;
                const int kc = kh * 2 + hi;
                bfr[nt][kh] = *(const short8*)&Bs[(row * 4 + (kc ^ (row & 3))) * 8];
            }
        #pragma unroll
        for (int mt = 0; mt < 2; mt++)
            #pragma unroll
            for (int nt = 0; nt < 2; nt++)
                #pragma unroll
                for (int kh = 0; kh < 2; kh++)
                    acc[mt][nt] = __builtin_amdgcn_mfma_f32_32x32x16_bf16(
                        af[mt][kh], bfr[nt][kh], acc[mt][nt], 0, 0, 0);
        __syncthreads();
    }

    #pragma unroll
    for (int mt = 0; mt < 2; mt++)
        #pragma unroll
        for (int nt = 0; nt < 2; nt++) {
            const int col = n0 + wn * 64 + nt * 32 + l32;
            float bval = 0.f;
            if (BIAS) bval = bias[col];
            #pragma unroll
            for (int reg = 0; reg < 16; reg++) {
                const int row = m0 + wm * 64 + mt * 32 + (reg & 3) + 8 * (reg >> 2) + 4 * hi;
                float v = acc[mt][nt][reg];
                if (ELU) { if (col < 2 * NC) v = (v > 0.f) ? v + 1.f : __expf(v); }
                if (BIAS) v += bval;
                if (sizeof(OutT) == 2) Cout[(size_t)row * LDC + col] = (OutT)f2bf(v);
                else                   Cout[(size_t)row * LDC + col] = (OutT)v;
            }
        }
}

// ---------- kv/ksum partials: per (slice, bh) block over 512 rows ----------
__global__ __launch_bounds__(256) void kv_ksum(const ushort* __restrict__ qkv,
                                               float* __restrict__ kvpart,
                                               float* __restrict__ kspart) {
    __shared__ ushort klds[128 * 64];
    __shared__ ushort vlds[128 * 64];
    __shared__ float  kvred[64 * 64];
    __shared__ float  ksred[4][64];
    const int bh = blockIdx.y, b = bh / NH, h = bh % NH;
    const int t = threadIdx.x, w = t >> 6, lane = t & 63, l16 = lane & 15, quad = lane >> 4;
    const int n0 = blockIdx.x * 512;
    const ushort* kbase = qkv + (size_t)(b * NN) * LDQKV + NC     + h * ND;
    const ushort* vbase = qkv + (size_t)(b * NN) * LDQKV + 2 * NC + h * ND;

    floatx4 acc[4][4] = {};
    floatx4 acc5[4] = {};
    short8 ones;
    #pragma unroll
    for (int j = 0; j < 8; j++) ones[j] = (l16 == 0) ? (short)0x3F80 : (short)0;

    const int rowT = t >> 3, ch = t & 7;

    for (int s = 0; s < 4; s++) {
        const int nb = n0 + s * 128;
        #pragma unroll
        for (int i = 0; i < 4; i++) {
            const size_t r = (size_t)(nb + i * 32 + rowT) * LDQKV + ch * 8;
            gl_lds16(kbase + r, klds + i * 2048 + w * 512);
            gl_lds16(vbase + r, vlds + i * 2048 + w * 512);
        }
        __syncthreads();
        short8 af[4], bfr[4];
        #pragma unroll
        for (int dt = 0; dt < 4; dt++) {
            short8 v;
            #pragma unroll
            for (int j = 0; j < 8; j++)
                v[j] = (short)klds[(w * 32 + quad * 8 + j) * 64 + dt * 16 + l16];
            af[dt] = v;
        }
        #pragma unroll
        for (int et = 0; et < 4; et++) {
            short8 v;
            #pragma unroll
            for (int j = 0; j < 8; j++)
                v[j] = (short)vlds[(w * 32 + quad * 8 + j) * 64 + et * 16 + l16];
            bfr[et] = v;
        }
        #pragma unroll
        for (int dt = 0; dt < 4; dt++) {
            #pragma unroll
            for (int et = 0; et < 4; et++)
                acc[dt][et] = __builtin_amdgcn_mfma_f32_16x16x32_bf16(af[dt], bfr[et], acc[dt][et], 0, 0, 0);
            acc5[dt] = __builtin_amdgcn_mfma_f32_16x16x32_bf16(af[dt], ones, acc5[dt], 0, 0, 0);
        }
        __syncthreads();
    }

    if (w == 0) {
        #pragma unroll
        for (int dt = 0; dt < 4; dt++)
            #pragma unroll
            for (int et = 0; et < 4; et++)
                #pragma unroll
                for (int r = 0; r < 4; r++)
                    kvred[(dt * 16 + quad * 4 + r) * 64 + et * 16 + l16] = acc[dt][et][r];
    }
    if (l16 == 0) {
        #pragma unroll
        for (int dt = 0; dt < 4; dt++)
            #pragma unroll
            for (int r = 0; r < 4; r++)
                ksred[w][dt * 16 + quad * 4 + r] = acc5[dt][r];
    }
    __syncthreads();
    if (w != 0) {
        #pragma unroll
        for (int dt = 0; dt < 4; dt++)
            #pragma unroll
            for (int et = 0; et < 4; et++)
                #pragma unroll
                for (int r = 0; r < 4; r++)
                    atomicAdd(&kvred[(dt * 16 + quad * 4 + r) * 64 + et * 16 + l16], acc[dt][et][r]);
    }
    __syncthreads();
    float* kvp = kvpart + ((size_t)blockIdx.x * 48 + bh) * 4096;
    for (int i = t; i < 4096; i += 256) kvp[i] = kvred[i];
    if (t < 64) kspart[((size_t)blockIdx.x * 48 + bh) * 64 + t] =
        ksred[0][t] + ksred[1][t] + ksred[2][t] + ksred[3][t];
}

// ---------- reduce partials ----------
__global__ __launch_bounds__(256) void reduce_kvks(const float* __restrict__ kvpart,
                                                   const float* __restrict__ kspart,
                                                   float* __restrict__ kvfinal,
                                                   float* __restrict__ ksfinal) {
    const int bh = blockIdx.y, t = threadIdx.x;
    if (blockIdx.x < 16) {
        const int i = blockIdx.x * 256 + t;
        float s = 0.f;
        #pragma unroll
        for (int p = 0; p < NSPLIT; p++) s += kvpart[((size_t)p * 48 + bh) * 4096 + i];
        kvfinal[(size_t)bh * 4096 + i] = s;
    } else if (t < 64) {
        float s = 0.f;
        #pragma unroll
        for (int p = 0; p < NSPLIT; p++) s += kspart[((size_t)p * 48 + bh) * 64 + t];
        ksfinal[bh * 64 + t] = s;
    }
}

// ---------- out_pre = (q @ kv) / (q . ksum + 1e-6), bf16 ----------
__global__ __launch_bounds__(256) void attn_apply(const ushort* __restrict__ qkv,
                                                  const float* __restrict__ kvfinal,
                                                  const float* __restrict__ ksfinal,
                                                  ushort* __restrict__ outpre) {
    __shared__ ushort kvb[64 * 80];
    const int bh = blockIdx.y, b = bh / NH, h = bh % NH;
    const int t = threadIdx.x, w = t >> 6, lane = t & 63, l16 = lane & 15, quad = lane >> 4;

    for (int i = t; i < 4096; i += 256) {
        const int d = i >> 6, e = i & 63;
        kvb[d * 80 + e] = f2bf(kvfinal[(size_t)bh * 4096 + i]);
    }
    for (int i = t; i < 1024; i += 256) {
        const int d = i >> 4, c = i & 15;
        kvb[d * 80 + 64 + c] = (c == 0) ? f2bf(ksfinal[bh * 64 + d]) : (ushort)0;
    }
    __syncthreads();

    short8 bfr[5][2];
    #pragma unroll
    for (int et = 0; et < 5; et++)
        #pragma unroll
        for (int ks = 0; ks < 2; ks++) {
            short8 v;
            #pragma unroll
            for (int j = 0; j < 8; j++)
                v[j] = (short)kvb[(ks * 32 + quad * 8 + j) * 80 + et * 16 + l16];
            bfr[et][ks] = v;
        }

    const ushort* qbase = qkv + (size_t)(b * NN) * LDQKV + h * ND;
    ushort* obase = outpre + (size_t)(b * NN) * NC + h * ND;
    const int n0 = blockIdx.x * 512;

    for (int it = 0; it < 8; it++) {
        const int nt = n0 + (it * 4 + w) * 16;
        const ushort* qp = qbase + (size_t)(nt + l16) * LDQKV + quad * 8;
        const short8 a0 = *(const short8*)qp;
        const short8 a1 = *(const short8*)(qp + 32);
        floatx4 acc[5] = {};
        #pragma unroll
        for (int et = 0; et < 5; et++) {
            acc[et] = __builtin_amdgcn_mfma_f32_16x16x32_bf16(a0, bfr[et][0], acc[et], 0, 0, 0);
            acc[et] = __builtin_amdgcn_mfma_f32_16x16x32_bf16(a1, bfr[et][1], acc[et], 0, 0, 0);
        }
        float dv[4];
        #pragma unroll
        for (int r = 0; r < 4; r++) dv[r] = __shfl(acc[4][r], lane & 48);
        #pragma unroll
        for (int et = 0; et < 4; et++)
            #pragma unroll
            for (int r = 0; r < 4; r++) {
                const float o = acc[et][r] / (dv[r] + 1e-6f);
                obase[(size_t)(nt + quad * 4 + r) * NC + et * 16 + l16] = f2bf(o);
            }
    }
}

extern "C" void kernel_launch(void* const* d_in, const int* in_sizes, int n_in,
                              void* d_out, int out_size, void* d_ws, size_t ws_size,
                              hipStream_t stream) {
    (void)in_sizes; (void)n_in; (void)out_size; (void)ws_size;
    const float* X     = (const float*)d_in[0];
    const float* Wqkv  = (const float*)d_in[1];
    const float* Wproj = (const float*)d_in[2];
    const float* bproj = (const float*)d_in[3];
    float* out = (float*)d_out;

    char* ws = (char*)d_ws;
    size_t off = 0;
    ushort* qkv     = (ushort*)(ws + off); off += (size_t)32768 * 2304 * 2;
    ushort* outpre  = (ushort*)(ws + off); off += (size_t)32768 * 768 * 2;
    ushort* xbf     = (ushort*)(ws + off); off += (size_t)32768 * 768 * 2;
    ushort* wqkvbf  = (ushort*)(ws + off); off += (size_t)2304 * 768 * 2;
    ushort* wprojbf = (ushort*)(ws + off); off += (size_t)768 * 768 * 2;
    float* kvpart  = (float*)xbf;                             // aliases dead xbf
    float* kspart  = kvpart + (size_t)NSPLIT * 48 * 4096;
    float* kvfinal = kspart + (size_t)NSPLIT * 48 * 64;
    float* ksfinal = kvfinal + (size_t)48 * 4096;

    const int ncvt = (32768 * 768 + 2304 * 768 + 768 * 768) / 8 / 256;
    cvt_all<<<ncvt, 256, 0, stream>>>(X, Wqkv, Wproj, xbf, wqkvbf, wprojbf);

    gemm_bt<LDQKV, true, false, ushort><<<dim3(18, 256), 256, 0, stream>>>(xbf, wqkvbf, nullptr, qkv, NC);
    kv_ksum<<<dim3(NSPLIT, 48), 256, 0, stream>>>(qkv, kvpart, kspart);
    reduce_kvks<<<dim3(17, 48), 256, 0, stream>>>(kvpart, kspart, kvfinal, ksfinal);
    attn_apply<<<dim3(NSPLIT, 48), 256, 0, stream>>>(qkv, kvfinal, ksfinal, outpre);
    gemm_bt<NC, false, true, float><<<dim3(6, 256), 256, 0, stream>>>(outpre, wprojbf, bproj, out, NC);
}